// Round 2
// baseline (7849.277 us; speedup 1.0000x reference)
//
#include <hip/hip_runtime.h>
#include <hip/hip_bf16.h>

typedef __hip_bfloat16 bf16;

#define T_  1024
#define D_  2048
#define H_  32
#define HD_ 64

static const size_t TT_ = (size_t)T_ * T_;
static const size_t TD_ = (size_t)T_ * D_;

__device__ __forceinline__ float toF(float x) { return x; }
__device__ __forceinline__ float toF(bf16 x) { return __bfloat162float(x); }

template <typename T> __device__ __forceinline__ T fromF(float v);
template <> __device__ __forceinline__ float fromF<float>(float v) { return v; }
template <> __device__ __forceinline__ bf16 fromF<bf16>(float v) { return __float2bfloat16(v); }

// ---------------------------------------------------------------------------
// Generic tiled GEMM: C[M,N] (+)= alpha * A[M,K] @ B[K,N]; row-major, batched
// via grid.z with element strides sA/sB/sC. 64x64 tile, BK=16, 256 threads,
// 4x4 outputs per thread.
// ---------------------------------------------------------------------------
template <typename TA, typename TB, typename TC, bool ACC>
__global__ void gemm_tiled(int M, int N, int K,
                           const TA* __restrict__ A, int lda, size_t sA,
                           const TB* __restrict__ B, int ldb, size_t sB,
                           TC* __restrict__ C, int ldc, size_t sC, float alpha)
{
    A += (size_t)blockIdx.z * sA;
    B += (size_t)blockIdx.z * sB;
    C += (size_t)blockIdx.z * sC;
    int row0 = blockIdx.y * 64, col0 = blockIdx.x * 64;
    __shared__ float As[16][68];
    __shared__ float Bs[16][68];
    int tid = threadIdx.x;
    int rb = (tid >> 4) << 2;
    int cb = (tid & 15) << 2;
    float acc[4][4] = {};
    for (int kk = 0; kk < K; kk += 16) {
        for (int i = tid; i < 1024; i += 256) {
            int m = i >> 4, k = i & 15;
            int gr = row0 + m, gk = kk + k;
            As[k][m] = (gr < M && gk < K) ? toF(A[(size_t)gr * lda + gk]) : 0.f;
        }
        for (int i = tid; i < 1024; i += 256) {
            int k = i >> 6, n = i & 63;
            int gk = kk + k, gc = col0 + n;
            Bs[k][n] = (gk < K && gc < N) ? toF(B[(size_t)gk * ldb + gc]) : 0.f;
        }
        __syncthreads();
#pragma unroll
        for (int k = 0; k < 16; k++) {
            float a[4], b[4];
#pragma unroll
            for (int j = 0; j < 4; j++) { a[j] = As[k][rb + j]; b[j] = Bs[k][cb + j]; }
#pragma unroll
            for (int i2 = 0; i2 < 4; i2++)
#pragma unroll
                for (int j = 0; j < 4; j++) acc[i2][j] += a[i2] * b[j];
        }
        __syncthreads();
    }
#pragma unroll
    for (int i2 = 0; i2 < 4; i2++) {
        int gr = row0 + rb + i2;
        if (gr >= M) continue;
#pragma unroll
        for (int j = 0; j < 4; j++) {
            int gc = col0 + cb + j;
            if (gc >= N) continue;
            float v = alpha * acc[i2][j];
            if (ACC) v += toF(C[(size_t)gr * ldc + gc]);
            C[(size_t)gr * ldc + gc] = fromF<TC>(v);
        }
    }
}

// ---------------------------------------------------------------------------
// pairdot: out[z][t][s] = dot64(X[t, head], Y[s, head]) with masking / beta.
// mode bit0: strict (s<t else 0); bit1: causal (s<=t else 0); bit2: *= beta[s]
// X,Y: [T, D] f32 (head offset applied). Grid (T/32, T/32, NH), block 256.
// ---------------------------------------------------------------------------
__global__ void pairdot(const float* __restrict__ X, const float* __restrict__ Y,
                        const float* __restrict__ beta, float* __restrict__ out,
                        int headStart, int mode)
{
    int z = blockIdx.z;
    int head = headStart + z;
    size_t hoff = (size_t)head * HD_;
    int t0 = blockIdx.y * 32, s0 = blockIdx.x * 32;
    __shared__ float Xs[64][33];
    __shared__ float Ys[64][33];
    int tid = threadIdx.x;
    for (int i = tid; i < 2048; i += 256) {
        int r = i >> 6, k = i & 63;
        Xs[k][r] = X[(size_t)(t0 + r) * D_ + hoff + k];
        Ys[k][r] = Y[(size_t)(s0 + r) * D_ + hoff + k];
    }
    __syncthreads();
    int row = tid >> 3;
    int cg = (tid & 7) << 2;
    float acc[4] = {0.f, 0.f, 0.f, 0.f};
#pragma unroll 8
    for (int k = 0; k < 64; k++) {
        float x = Xs[k][row];
#pragma unroll
        for (int j = 0; j < 4; j++) acc[j] += x * Ys[k][cg + j];
    }
    int t = t0 + row;
    float* orow = out + (size_t)z * TT_ + (size_t)t * T_;
#pragma unroll
    for (int j = 0; j < 4; j++) {
        int s = s0 + cg + j;
        float v = acc[j];
        if (mode & 1) v = (s < t) ? v : 0.f;
        if (mode & 2) v = (s <= t) ? v : 0.f;
        if (mode & 4) v *= beta[(size_t)s * H_ + head];
        orow[s] = v;
    }
}

// ---------------------------------------------------------------------------
// diag_inv: invert the 64x64 unit-lower diagonal blocks of (I + Lb).
// Lb diag blocks are strictly lower (upper+diag already zero).
// Grid (16, NH), block 64. Each thread owns one column of the inverse.
// ---------------------------------------------------------------------------
__global__ void diag_inv(const float* __restrict__ Lb, float* __restrict__ Minv)
{
    int bi = blockIdx.x, z = blockIdx.y;
    const float* Lh = Lb + (size_t)z * TT_;
    __shared__ float Nb[64][65];
    __shared__ float Xc[64][65];
    int tid = threadIdx.x;
    for (int i = tid; i < 4096; i += 64) {
        int r = i >> 6, c = i & 63;
        Nb[r][c] = Lh[(size_t)(bi * 64 + r) * T_ + bi * 64 + c];
    }
    __syncthreads();
    int j = tid;  // column owned by this thread; no cross-thread deps
    for (int t = 0; t < 64; t++) {
        float v = (t == j) ? 1.f : 0.f;
        for (int i = 0; i < t; i++) v -= Nb[t][i] * Xc[i][j];
        Xc[t][j] = v;
    }
    __syncthreads();
    float* Mo = Minv + ((size_t)z * 16 + bi) * 4096;
    for (int i = tid; i < 4096; i += 64) Mo[i] = Xc[i >> 6][i & 63];
}

// ---------------------------------------------------------------------------
// diag_apply: C[block-row bi, col-tile ct] = Minv_bi @ C[block-row bi, ct]
// in place (block owns its 64x64 region). Grid (bi+1, NH), block 256.
// ---------------------------------------------------------------------------
__global__ void diag_apply(float* __restrict__ Cm, const float* __restrict__ Minv, int bi)
{
    int ct = blockIdx.x, z = blockIdx.y;
    __shared__ float Mi[64][65];
    __shared__ float Cb[64][65];
    int tid = threadIdx.x;
    const float* Mo = Minv + ((size_t)z * 16 + bi) * 4096;
    for (int i = tid; i < 4096; i += 256) Mi[i >> 6][i & 63] = Mo[i];
    float* Ch = Cm + (size_t)z * TT_;
    for (int i = tid; i < 4096; i += 256) {
        int r = i >> 6, c = i & 63;
        Cb[r][c] = Ch[(size_t)(bi * 64 + r) * T_ + ct * 64 + c];
    }
    __syncthreads();
    int col = tid & 63, rg = tid >> 6;
    float res[16];
    for (int rr = 0; rr < 16; rr++) {
        int row = rg * 16 + rr;
        float v = 0.f;
#pragma unroll 8
        for (int k = 0; k < 64; k++) v += Mi[row][k] * Cb[k][col];
        res[rr] = v;
    }
    for (int rr = 0; rr < 16; rr++) {
        int row = rg * 16 + rr;
        Ch[(size_t)(bi * 64 + row) * T_ + ct * 64 + col] = res[rr];
    }
}

// ---------------------------------------------------------------------------
// gemm_sub_causal: Ab[t,s] -= sum_k E[t,k] * C[k,s], lower tiles only, with
// triangular k-window [s0, t0+64). Grid (16,16,NH), block 256.
// ---------------------------------------------------------------------------
__global__ void gemm_sub_causal(const float* __restrict__ E, const float* __restrict__ Cm,
                                float* __restrict__ Ab)
{
    int z = blockIdx.z;
    int t0 = blockIdx.y * 64, s0 = blockIdx.x * 64;
    if (s0 > t0) return;
    const float* Eh = E + (size_t)z * TT_;
    const float* Ch = Cm + (size_t)z * TT_;
    float* Ah = Ab + (size_t)z * TT_;
    __shared__ float As[16][68];
    __shared__ float Bs[16][68];
    int tid = threadIdx.x;
    int rb = (tid >> 4) << 2;
    int cb = (tid & 15) << 2;
    float acc[4][4] = {};
    int kEnd = t0 + 64;
    for (int kk = s0; kk < kEnd; kk += 16) {
        for (int i = tid; i < 1024; i += 256) {
            int m = i >> 4, k = i & 15;
            As[k][m] = Eh[(size_t)(t0 + m) * T_ + kk + k];
        }
        for (int i = tid; i < 1024; i += 256) {
            int k = i >> 6, n = i & 63;
            Bs[k][n] = Ch[(size_t)(kk + k) * T_ + s0 + n];
        }
        __syncthreads();
#pragma unroll
        for (int k = 0; k < 16; k++) {
            float a[4], b[4];
#pragma unroll
            for (int j = 0; j < 4; j++) { a[j] = As[k][rb + j]; b[j] = Bs[k][cb + j]; }
#pragma unroll
            for (int i2 = 0; i2 < 4; i2++)
#pragma unroll
                for (int j = 0; j < 4; j++) acc[i2][j] += a[i2] * b[j];
        }
        __syncthreads();
    }
#pragma unroll
    for (int i2 = 0; i2 < 4; i2++)
#pragma unroll
        for (int j = 0; j < 4; j++)
            Ah[(size_t)(t0 + rb + i2) * T_ + s0 + cb + j] -= acc[i2][j];
}

// ---------------------------------------------------------------------------
// beta/gate elementwise + cumsum + conv/silu/norm + softmax
// ---------------------------------------------------------------------------
__global__ void bg_fuse(const float* __restrict__ hb, const float* __restrict__ hg,
                        const float* __restrict__ bbt, const float* __restrict__ bgp,
                        float* __restrict__ beta, float* __restrict__ G)
{
    int idx = blockIdx.x * 256 + threadIdx.x;
    if (idx >= T_ * H_) return;
    int hh = idx & (H_ - 1);
    float xb = hb[idx] + bbt[hh];
    beta[idx] = 2.f / (1.f + expf(-xb));
    float xg = hg[idx] + bgp[hh];
    G[idx] = (xg >= 0.f) ? -log1pf(expf(-xg)) : (xg - log1pf(expf(xg)));
}

__global__ void cumsum_g(float* __restrict__ G)
{
    int h = threadIdx.x;  // 32 threads, one per head
    float acc = 0.f;
    for (int t = 0; t < T_; t++) {
        acc += G[(size_t)t * H_ + h];
        G[(size_t)t * H_ + h] = acc;
    }
}

__global__ void conv_silu_norm(const float* __restrict__ wr, const float* __restrict__ convw,
                               float* __restrict__ wf)
{
    int b = blockIdx.x;
    int t = b >> 5, h = b & 31;
    int d = threadIdx.x;
    int c = h * 64 + d;
    float c0 = convw[c * 3 + 0];
    float c1 = convw[c * 3 + 1];
    float c2 = convw[c * 3 + 2];
    float x = c2 * wr[(size_t)t * D_ + c];
    if (t >= 1) x += c1 * wr[(size_t)(t - 1) * D_ + c];
    if (t >= 2) x += c0 * wr[(size_t)(t - 2) * D_ + c];
    float y = x / (1.f + expf(-x));  // silu
    float ss = y * y;
    for (int off = 32; off > 0; off >>= 1) ss += __shfl_xor(ss, off, 64);
    wf[(size_t)t * D_ + c] = y * rsqrtf(ss);
}

// softmax over row t (s <= t) with gate: logits = A/8 + G[t]-G[s]; G[t] cancels.
__global__ void softmax_rows(float* __restrict__ Ab, const float* __restrict__ G, int headStart)
{
    int t = blockIdx.x, z = blockIdx.y;
    int head = headStart + z;
    float* row = Ab + (size_t)z * TT_ + (size_t)t * T_;
    int tid = threadIdx.x;
    int len = t + 1;
    float lv[4];
    int cnt = 0;
    float m = -1e30f;
    for (int s = tid; s < len; s += 256) {
        float l = row[s] * 0.125f - G[(size_t)s * H_ + head];
        lv[cnt++] = l;
        if (l > m) m = l;
    }
    __shared__ float red[256];
    red[tid] = m; __syncthreads();
    for (int off = 128; off > 0; off >>= 1) {
        if (tid < off) red[tid] = fmaxf(red[tid], red[tid + off]);
        __syncthreads();
    }
    m = red[0]; __syncthreads();
    float sum = 0.f;
    for (int i = 0; i < cnt; i++) { lv[i] = expf(lv[i] - m); sum += lv[i]; }
    red[tid] = sum; __syncthreads();
    for (int off = 128; off > 0; off >>= 1) {
        if (tid < off) red[tid] += red[tid + off];
        __syncthreads();
    }
    float inv = 1.f / red[0];
    cnt = 0;
    for (int s = tid; s < len; s += 256) row[s] = lv[cnt++] * inv;
    for (int s = len + tid; s < T_; s += 256) row[s] = 0.f;
}

// ---------------------------------------------------------------------------
extern "C" void kernel_launch(void* const* d_in, const int* in_sizes, int n_in,
                              void* d_out, int out_size, void* d_ws, size_t ws_size,
                              hipStream_t stream)
{
    const float* h     = (const float*)d_in[0];
    const float* Wq    = (const float*)d_in[1];
    const float* Wk    = (const float*)d_in[2];
    const float* Wv    = (const float*)d_in[3];
    const float* Ww1   = (const float*)d_in[4];
    const float* Ww2   = (const float*)d_in[5];
    const float* convw = (const float*)d_in[6];
    const float* Wbt   = (const float*)d_in[7];
    const float* bbt   = (const float*)d_in[8];
    const float* Wg    = (const float*)d_in[9];
    const float* bgp   = (const float*)d_in[10];
    const float* Wo    = (const float*)d_in[11];
    float* out = (float*)d_out;

    float* ws = (float*)d_ws;
    size_t off = 0;
    float* qf = ws + off; off += TD_;
    float* kf = ws + off; off += TD_;
    float* vf = ws + off; off += TD_;
    float* wr = ws + off; off += TD_;
    float* wf = ws + off; off += TD_;
    float* of = ws + off; off += TD_;
    float* w1 = ws + off; off += (size_t)T_ * 32;
    float* hb = ws + off; off += (size_t)T_ * 32;
    float* hg = ws + off; off += (size_t)T_ * 32;
    float* betaB = ws + off; off += (size_t)T_ * H_;
    float* Gb = ws + off; off += (size_t)T_ * H_;
    size_t fixedF = off;
    size_t capF = ws_size / 4;
    size_t perHead = 3 * TT_ + (size_t)16 * 64 * 64;
    int NH = 32;
    while (NH > 1 && fixedF + (size_t)NH * perHead > capF) NH >>= 1;
    float* Lb = ws + off; off += (size_t)NH * TT_;   // L*beta, later reused as A/P
    float* Cm = ws + off; off += (size_t)NH * TT_;   // strict(S) -> C (solved in place)
    float* Em = ws + off; off += (size_t)NH * TT_;   // causal(E)*beta
    float* Mv = ws + off; off += (size_t)NH * 16 * 64 * 64;

    dim3 blk(256);

    // Projections
    gemm_tiled<float, float, float, false><<<dim3(32, 16, 1), blk, 0, stream>>>(
        T_, D_, D_, h, D_, 0, Wq, D_, 0, qf, D_, 0, 1.f);
    gemm_tiled<float, float, float, false><<<dim3(32, 16, 1), blk, 0, stream>>>(
        T_, D_, D_, h, D_, 0, Wk, D_, 0, kf, D_, 0, 1.f);
    gemm_tiled<float, float, float, false><<<dim3(32, 16, 1), blk, 0, stream>>>(
        T_, D_, D_, h, D_, 0, Wv, D_, 0, vf, D_, 0, 1.f);
    gemm_tiled<float, float, float, false><<<dim3(1, 16, 1), blk, 0, stream>>>(
        T_, 32, D_, h, D_, 0, Ww1, 32, 0, w1, 32, 0, 1.f);
    gemm_tiled<float, float, float, false><<<dim3(32, 16, 1), blk, 0, stream>>>(
        T_, D_, 32, w1, 32, 0, Ww2, D_, 0, wr, D_, 0, 1.f);
    gemm_tiled<float, float, float, false><<<dim3(1, 16, 1), blk, 0, stream>>>(
        T_, 32, D_, h, D_, 0, Wbt, 32, 0, hb, 32, 0, 1.f);
    gemm_tiled<float, float, float, false><<<dim3(1, 16, 1), blk, 0, stream>>>(
        T_, 32, D_, h, D_, 0, Wg, 32, 0, hg, 32, 0, 1.f);
    bg_fuse<<<dim3((T_ * H_ + 255) / 256), blk, 0, stream>>>(hb, hg, bbt, bgp, betaB, Gb);
    cumsum_g<<<dim3(1), dim3(32), 0, stream>>>(Gb);
    conv_silu_norm<<<dim3(T_ * H_), dim3(64), 0, stream>>>(wr, convw, wf);

    int nChunks = H_ / NH;
    for (int c = 0; c < nChunks; c++) {
        int hs = c * NH;
        // L*beta (strict), strict(S) -> Cm, causal(E)*beta
        pairdot<<<dim3(32, 32, NH), blk, 0, stream>>>(wf, wf, betaB, Lb, hs, 1 | 4);
        pairdot<<<dim3(32, 32, NH), blk, 0, stream>>>(wf, kf, betaB, Cm, hs, 1);
        pairdot<<<dim3(32, 32, NH), blk, 0, stream>>>(qf, wf, betaB, Em, hs, 2 | 4);
        // blocked unit-lower solve
        diag_inv<<<dim3(16, NH), dim3(64), 0, stream>>>(Lb, Mv);
        for (int bi = 0; bi < 16; bi++) {
            if (bi > 0)
                gemm_tiled<float, float, float, true><<<dim3(bi, 1, NH), blk, 0, stream>>>(
                    64, bi * 64, bi * 64,
                    Lb + (size_t)bi * 64 * T_, T_, TT_,
                    Cm, T_, TT_,
                    Cm + (size_t)bi * 64 * T_, T_, TT_, -1.f);
            diag_apply<<<dim3(bi + 1, NH), blk, 0, stream>>>(Cm, Mv, bi);
        }
        // A = Dqk - EB @ C  (Dqk into Lb buffer, then subtract)
        pairdot<<<dim3(32, 32, NH), blk, 0, stream>>>(qf, kf, betaB, Lb, hs, 0);
        gemm_sub_causal<<<dim3(16, 16, NH), blk, 0, stream>>>(Em, Cm, Lb);
        // gated causal softmax (P overwrites A in Lb)
        softmax_rows<<<dim3(T_, NH), blk, 0, stream>>>(Lb, Gb, hs);
        // O_head = P @ v_head
        gemm_tiled<float, float, float, false><<<dim3(1, 16, NH), blk, 0, stream>>>(
            T_, 64, T_, Lb, T_, TT_,
            vf + (size_t)hs * 64, D_, 64,
            of + (size_t)hs * 64, D_, 64, 1.f);
    }
    // out = of @ Wo (f32 store)
    gemm_tiled<float, float, float, false><<<dim3(32, 16, 1), blk, 0, stream>>>(
        T_, D_, D_, of, D_, 0, Wo, D_, 0, out, D_, 0, 1.f);
}